// Round 11
// baseline (167.711 us; speedup 1.0000x reference)
//
#include <hip/hip_runtime.h>

// N=100000 nodes, E=1600000 edges, D=64.
// Pipeline (2 launches):
//  K1 bin8_conv (1024 thr): per 8192-edge tile, LDS counting sort by 256-row
//     bucket (shfl scan) -> coalesced tilebuf + csumG; + bf16 conv. (unchanged)
//  K2 agg11 (512 thr, grid 782 = 2 twin blocks per 256-row bucket, all
//     co-resident): each twin fetches the bucket's flat edge stream but
//     counts/scatters/gathers only its 128-row half; 8 gather chains/group.
#define D_FEAT 64
#define CB 256                // rows per bucket -> nb2 = 391
#define CBITS 8
#define HB 128                // rows per agg half-block
#define NBC 448               // padded bucket-scan width (>= nb2), 7 waves x 64
#define E_BLK 8192            // edges per tile -> ebt = 196
#define TMAX 256              // padded tile count (>= ebt)
#define SCAP 2560             // scol capacity = flat chunk size (half <= chunk)
#define PKN 5                 // ceil(SCAP/512) reg-cached packed edges

__device__ inline unsigned short f2bf(float f) {
    unsigned u = __float_as_uint(f);
    u += 0x7FFFu + ((u >> 16) & 1u);   // RNE
    return (unsigned short)(u >> 16);
}
__device__ inline float bf_lo(unsigned u) { return __uint_as_float(u << 16); }
__device__ inline float bf_hi(unsigned u) { return __uint_as_float(u & 0xFFFF0000u); }

// ---------------- K1: tile counting sort (shfl scan) + bf16 conv -----------
__global__ __launch_bounds__(1024, 8)
void bin8_conv_kernel(const int* __restrict__ row, const int* __restrict__ col,
                      int* __restrict__ tilebuf,   // [ebt][E_BLK] bucket-sorted
                      int* __restrict__ csumG,     // [ebt][nb2+1] offsets
                      int n_edges, int ebt, int nb2,
                      const float* __restrict__ feat,
                      unsigned short* __restrict__ feat_bf, int n4) {
    int gb = blockIdx.x;
    int t = threadIdx.x;
    if (gb < ebt) {
        __shared__ int hist[NBC];      // counts -> absolute cursors
        __shared__ int ebuf[E_BLK];    // 32 KB sorted (pk = lr<<17 | col)
        __shared__ int wpart[16];
        int w = t >> 6, lane = t & 63;
        for (int i = t; i < NBC; i += 1024) hist[i] = 0;
        __syncthreads();
        int e0 = gb * E_BLK;
        int ne = min(E_BLK, n_edges - e0);
        int rr[8], cc[8];
        #pragma unroll
        for (int k = 0; k < 8; ++k) {
            int i = t + k * 1024;
            if (i < ne) { rr[k] = row[e0 + i]; cc[k] = col[e0 + i]; }
            else rr[k] = -1;
        }
        #pragma unroll
        for (int k = 0; k < 8; ++k)
            if (rr[k] >= 0) atomicAdd(&hist[rr[k] >> CBITS], 1);
        __syncthreads();
        // shfl scan over NBC=448: waves 0..6
        int idx = w * 64 + lane;
        int v = 0, incl = 0;
        if (w < 7) {
            v = hist[idx];
            incl = v;
            #pragma unroll
            for (int o = 1; o < 64; o <<= 1) {
                int up = __shfl_up(incl, o, 64);
                if (lane >= o) incl += up;
            }
            if (lane == 63) wpart[w] = incl;
        }
        __syncthreads();
        if (t == 0) {
            int run = 0;
            #pragma unroll
            for (int k = 0; k < 7; ++k) { int x = wpart[k]; wpart[k] = run; run += x; }
        }
        __syncthreads();
        if (w < 7) {
            int excl = incl - v + wpart[w];
            if (idx < nb2) {
                csumG[(size_t)gb * (nb2 + 1) + idx] = excl;
                hist[idx] = excl;      // absolute scatter cursor
            }
        }
        if (t == 0) csumG[(size_t)gb * (nb2 + 1) + nb2] = ne;
        __syncthreads();
        #pragma unroll
        for (int k = 0; k < 8; ++k) {
            if (rr[k] >= 0) {
                int b = rr[k] >> CBITS;
                int pos = atomicAdd(&hist[b], 1);
                ebuf[pos] = ((rr[k] & (CB - 1)) << 17) | cc[k];  // col < 2^17
            }
        }
        __syncthreads();
        for (int i = t; i < ne; i += 1024)
            tilebuf[(size_t)gb * E_BLK + i] = ebuf[i];           // coalesced
    } else {
        int i = (gb - ebt) * 1024 + t;
        if (i < n4) {
            float4 f = reinterpret_cast<const float4*>(feat)[i];
            ushort4 u;
            u.x = f2bf(f.x); u.y = f2bf(f.y); u.z = f2bf(f.z); u.w = f2bf(f.w);
            reinterpret_cast<ushort4*>(feat_bf)[i] = u;
        }
    }
}

// ---------------- K2: twin half-bucket sort + 8-chain register gather ------
template<int BF>
__global__ __launch_bounds__(512, 8)
void agg11_kernel(const float* __restrict__ feat,
                  const unsigned short* __restrict__ feat_bf,
                  const int* __restrict__ tilebuf,
                  const int* __restrict__ csumG,
                  float* __restrict__ out, int n_nodes, int ebt, int nb2) {
    __shared__ int tstart[TMAX], tlen[TMAX], psum[TMAX];   // 3 KB
    __shared__ int scol[SCAP];                             // 10 KB
    __shared__ int cnt[HB], incl[HB], cur[HB], ddeg[HB];   // 2 KB
    __shared__ int wpart[8];

    int blk = blockIdx.x;
    int cb = blk >> 1;            // 256-row bucket
    int half = blk & 1;           // 128-row half
    int t = threadIdx.x;
    int w = t >> 6, lane = t & 63;
    int g = w * 8 + (lane >> 3);  // 64 groups of 8 lanes
    int sub = lane & 7;
    int rA = g;                   // group's two local rows
    int rB = g + 64;

    for (int i = t; i < TMAX; i += 512) {
        int s = 0, l = 0;
        if (i < ebt) {
            s = csumG[(size_t)i * (nb2 + 1) + cb];
            l = csumG[(size_t)i * (nb2 + 1) + cb + 1] - s;
        }
        tstart[i] = s; tlen[i] = l;
    }
    if (t < HB) ddeg[t] = 0;
    __syncthreads();
    // inclusive shfl scan of tlen over TMAX=256: waves 0..3
    {
        int idx = w * 64 + lane;
        int v = 0, ic = 0;
        if (w < 4) {
            v = tlen[idx];
            ic = v;
            #pragma unroll
            for (int o = 1; o < 64; o <<= 1) {
                int up = __shfl_up(ic, o, 64);
                if (lane >= o) ic += up;
            }
            if (lane == 63) wpart[w] = ic;
        }
        __syncthreads();
        if (t == 0) {
            int run = 0;
            #pragma unroll
            for (int k = 0; k < 4; ++k) { int x = wpart[k]; wpart[k] = run; run += x; }
        }
        __syncthreads();
        if (w < 4) psum[idx] = ic + wpart[w];
        __syncthreads();
    }
    int total = psum[ebt - 1];

    float acc[16];
    #pragma unroll
    for (int k = 0; k < 16; ++k) acc[k] = 0.f;

#define GATHER(cv, o0)                                                         \
    do {                                                                       \
        if (BF) {                                                              \
            uint4 d = *reinterpret_cast<const uint4*>(                         \
                feat_bf + (size_t)(cv)*D_FEAT + sub * 8);                      \
            acc[o0+0] += bf_lo(d.x); acc[o0+1] += bf_hi(d.x);                  \
            acc[o0+2] += bf_lo(d.y); acc[o0+3] += bf_hi(d.y);                  \
            acc[o0+4] += bf_lo(d.z); acc[o0+5] += bf_hi(d.z);                  \
            acc[o0+6] += bf_lo(d.w); acc[o0+7] += bf_hi(d.w);                  \
        } else {                                                               \
            float4 x0 = *reinterpret_cast<const float4*>(                      \
                feat + (size_t)(cv)*D_FEAT + sub * 8);                         \
            float4 x1 = *reinterpret_cast<const float4*>(                      \
                feat + (size_t)(cv)*D_FEAT + sub * 8 + 4);                     \
            acc[o0+0] += x0.x; acc[o0+1] += x0.y;                              \
            acc[o0+2] += x0.z; acc[o0+3] += x0.w;                              \
            acc[o0+4] += x1.x; acc[o0+5] += x1.y;                              \
            acc[o0+6] += x1.z; acc[o0+7] += x1.w;                              \
        }                                                                      \
    } while (0)

    // chunk loop over the bucket's flat edge stream; chunk=SCAP so this
    // half's per-chunk edges always fit scol (any input, no fallback)
    for (int L = 0; L < total; L += SCAP) {
        int R = min(L + SCAP, total);
        if (t < HB) cnt[t] = 0;
        __syncthreads();
        // fetch flat edges via binary search on psum; cache pk in regs
        int pkr[PKN];
        #pragma unroll
        for (int k = 0; k < PKN; ++k) {
            int j = L + t + k * 512;
            pkr[k] = -1;
            if (j < R) {
                int lo = 0, hi = ebt - 1;
                while (lo < hi) { int mid = (lo + hi) >> 1;
                                  if (psum[mid] > j) hi = mid; else lo = mid + 1; }
                int local = j - (psum[lo] - tlen[lo]);
                int pk = tilebuf[(size_t)lo * E_BLK + tstart[lo] + local];
                if ((int)(((unsigned)pk) >> 17 >> 7) == half) pkr[k] = pk;
            }
        }
        #pragma unroll
        for (int k = 0; k < PKN; ++k)
            if (pkr[k] >= 0) atomicAdd(&cnt[(((unsigned)pkr[k]) >> 17) & (HB - 1)], 1);
        __syncthreads();
        // inclusive shfl scan of cnt over HB=128: waves 0..1
        {
            int idx = w * 64 + lane;
            int v = 0, ic = 0;
            if (w < 2) {
                v = cnt[idx];
                ic = v;
                #pragma unroll
                for (int o = 1; o < 64; o <<= 1) {
                    int up = __shfl_up(ic, o, 64);
                    if (lane >= o) ic += up;
                }
                if (lane == 63) wpart[w] = ic;
            }
            __syncthreads();
            if (t == 0) { int x = wpart[0]; wpart[0] = 0; wpart[1] = x; }
            __syncthreads();
            if (w < 2) {
                int ival = ic + wpart[w];
                incl[idx] = ival;
                cur[idx] = ival - v;
                ddeg[idx] += v;
            }
            __syncthreads();
        }
        // scatter cols row-grouped into scol
        #pragma unroll
        for (int k = 0; k < PKN; ++k) {
            if (pkr[k] >= 0) {
                int key = (((unsigned)pkr[k]) >> 17) & (HB - 1);
                scol[atomicAdd(&cur[key], 1)] = pkr[k] & 0x1FFFF;
            }
        }
        __syncthreads();
        // gather: 2 rows per 8-lane group, j-unroll x4 -> 8 chains in flight
        int cA = cnt[rA], sA = incl[rA] - cA;
        int cB2 = cnt[rB], sB = incl[rB] - cB2;
        int m = max(cA, cB2);
        for (int j = 0; j < m; j += 4) {
            int c00 = (j < cA)      ? scol[sA + j]     : -1;
            int c01 = (j + 1 < cA)  ? scol[sA + j + 1] : -1;
            int c02 = (j + 2 < cA)  ? scol[sA + j + 2] : -1;
            int c03 = (j + 3 < cA)  ? scol[sA + j + 3] : -1;
            int c10 = (j < cB2)     ? scol[sB + j]     : -1;
            int c11 = (j + 1 < cB2) ? scol[sB + j + 1] : -1;
            int c12 = (j + 2 < cB2) ? scol[sB + j + 2] : -1;
            int c13 = (j + 3 < cB2) ? scol[sB + j + 3] : -1;
            if (c00 >= 0) GATHER(c00, 0);
            if (c10 >= 0) GATHER(c10, 8);
            if (c01 >= 0) GATHER(c01, 0);
            if (c11 >= 0) GATHER(c11, 8);
            if (c02 >= 0) GATHER(c02, 0);
            if (c12 >= 0) GATHER(c12, 8);
            if (c03 >= 0) GATHER(c03, 0);
            if (c13 >= 0) GATHER(c13, 8);
        }
        __syncthreads();   // scol/cnt reused next chunk
    }
#undef GATHER

    // epilogue: out[r] = feat[r] + acc/max(deg,1)
    int r0 = cb * CB + half * HB;
    {
        int r = r0 + rA;
        if (r < n_nodes) {
            float inv = 1.0f / fmaxf((float)ddeg[rA], 1.0f);
            size_t off = (size_t)r * D_FEAT + sub * 8;
            float4 f0 = *reinterpret_cast<const float4*>(feat + off);
            float4 f1 = *reinterpret_cast<const float4*>(feat + off + 4);
            float4 o0, o1;
            o0.x = f0.x + acc[0] * inv; o0.y = f0.y + acc[1] * inv;
            o0.z = f0.z + acc[2] * inv; o0.w = f0.w + acc[3] * inv;
            o1.x = f1.x + acc[4] * inv; o1.y = f1.y + acc[5] * inv;
            o1.z = f1.z + acc[6] * inv; o1.w = f1.w + acc[7] * inv;
            *reinterpret_cast<float4*>(out + off) = o0;
            *reinterpret_cast<float4*>(out + off + 4) = o1;
        }
        r = r0 + rB;
        if (r < n_nodes) {
            float inv = 1.0f / fmaxf((float)ddeg[rB], 1.0f);
            size_t off = (size_t)r * D_FEAT + sub * 8;
            float4 f0 = *reinterpret_cast<const float4*>(feat + off);
            float4 f1 = *reinterpret_cast<const float4*>(feat + off + 4);
            float4 o0, o1;
            o0.x = f0.x + acc[8]  * inv; o0.y = f0.y + acc[9]  * inv;
            o0.z = f0.z + acc[10] * inv; o0.w = f0.w + acc[11] * inv;
            o1.x = f1.x + acc[12] * inv; o1.y = f1.y + acc[13] * inv;
            o1.z = f1.z + acc[14] * inv; o1.w = f1.w + acc[15] * inv;
            *reinterpret_cast<float4*>(out + off) = o0;
            *reinterpret_cast<float4*>(out + off + 4) = o1;
        }
    }
}

extern "C" void kernel_launch(void* const* d_in, const int* in_sizes, int n_in,
                              void* d_out, int out_size, void* d_ws, size_t ws_size,
                              hipStream_t stream) {
    const float* feat = (const float*)d_in[0];
    const int* row = (const int*)d_in[1];
    const int* col = (const int*)d_in[2];
    float* out = (float*)d_out;

    const int n_nodes = in_sizes[0] / D_FEAT;
    const int n_edges = in_sizes[1];
    const int nb2 = (n_nodes + CB - 1) / CB;              // 391 (<= NBC)
    const int ebt = (n_edges + E_BLK - 1) / E_BLK;        // 196 (<= TMAX)
    const int n4 = n_nodes * D_FEAT / 4;                  // 1.6M float4s

    size_t tb_bytes  = (size_t)ebt * E_BLK * 4;           // 6.4 MB
    size_t cs_bytes  = (size_t)ebt * (nb2 + 1) * 4;       // 0.31 MB
    size_t bf_bytes  = (size_t)n_nodes * D_FEAT * 2;      // 12.8 MB

    size_t lean_need = tb_bytes + cs_bytes + 256;
    size_t fat_need  = lean_need + ((bf_bytes + 63) & ~(size_t)63);
    bool fat = (ws_size >= fat_need);

    char* ws = (char*)d_ws;
    size_t p = 0;
    int* tilebuf = (int*)(ws + p); p += tb_bytes;
    int* csumG   = (int*)(ws + p); p += cs_bytes;
    p = (p + 63) & ~(size_t)63;
    unsigned short* feat_bf = nullptr;
    if (fat) { feat_bf = (unsigned short*)(ws + p); }

    {
        int conv_blocks = fat ? (n4 + 1023) / 1024 : 0;
        bin8_conv_kernel<<<ebt + conv_blocks, 1024, 0, stream>>>(
            row, col, tilebuf, csumG, n_edges, ebt, nb2,
            feat, feat_bf, fat ? n4 : 0);
    }
    if (fat) {
        agg11_kernel<1><<<nb2 * 2, 512, 0, stream>>>(
            feat, feat_bf, tilebuf, csumG, out, n_nodes, ebt, nb2);
    } else {
        agg11_kernel<0><<<nb2 * 2, 512, 0, stream>>>(
            feat, nullptr, tilebuf, csumG, out, n_nodes, ebt, nb2);
    }
}

// Round 12
// 127.420 us; speedup vs baseline: 1.3162x; 1.3162x over previous
//
#include <hip/hip_runtime.h>

// N=100000 nodes, E=1600000 edges, D=64.
// Pipeline (2 launches):
//  K1 bin9_conv (1024 thr): per 4096-edge tile (391 sort blocks > 256 CUs),
//     LDS counting sort by 256-row bucket (shfl scan) -> coalesced tilebuf +
//     csumG; + bf16 conv blocks in the same launch.
//  K2 agg10 (1024 thr, block = 256-row bucket, grid 391): flat binary-search
//     edge fetch (reg-cached), 256-key LDS counting sort (shfl scan),
//     2-rows-per-8-lane-group gather with x2 j-unroll = 4 chains/group.
//     (proven 46.2 us in round 10; only the tile-scan width changed)
#define D_FEAT 64
#define CB 256                // rows per bucket -> nb2 = 391
#define CBITS 8
#define NBC 448               // padded bucket-scan width (>= nb2), 7 waves x 64
#define E_BLK 4096            // edges per tile -> ebt = 391
#define TMAX 512              // padded tile storage (>= ebt)
#define TSCAN 448             // padded tile-scan width (>= ebt), 7 waves x 64
#define SCAP 4608             // scol chunk capacity (bucket mean 4096, sd 64)
#define PKN 5                 // ceil(SCAP/1024) reg-cached packed edges

__device__ inline unsigned short f2bf(float f) {
    unsigned u = __float_as_uint(f);
    u += 0x7FFFu + ((u >> 16) & 1u);   // RNE
    return (unsigned short)(u >> 16);
}
__device__ inline float bf_lo(unsigned u) { return __uint_as_float(u << 16); }
__device__ inline float bf_hi(unsigned u) { return __uint_as_float(u & 0xFFFF0000u); }

// ---------------- K1: tile counting sort (shfl scan) + bf16 conv -----------
__global__ __launch_bounds__(1024, 8)
void bin9_conv_kernel(const int* __restrict__ row, const int* __restrict__ col,
                      int* __restrict__ tilebuf,   // [ebt][E_BLK] bucket-sorted
                      int* __restrict__ csumG,     // [ebt][nb2+1] offsets
                      int n_edges, int ebt, int nb2,
                      const float* __restrict__ feat,
                      unsigned short* __restrict__ feat_bf, int n4) {
    int gb = blockIdx.x;
    int t = threadIdx.x;
    if (gb < ebt) {
        __shared__ int hist[NBC];      // counts -> absolute cursors
        __shared__ int ebuf[E_BLK];    // 16 KB sorted (pk = lr<<17 | col)
        __shared__ int wpart[8];
        int w = t >> 6, lane = t & 63;
        for (int i = t; i < NBC; i += 1024) hist[i] = 0;
        __syncthreads();
        int e0 = gb * E_BLK;
        int ne = min(E_BLK, n_edges - e0);
        int rr[4], cc[4];
        #pragma unroll
        for (int k = 0; k < 4; ++k) {
            int i = t + k * 1024;
            if (i < ne) { rr[k] = row[e0 + i]; cc[k] = col[e0 + i]; }
            else rr[k] = -1;
        }
        #pragma unroll
        for (int k = 0; k < 4; ++k)
            if (rr[k] >= 0) atomicAdd(&hist[rr[k] >> CBITS], 1);
        __syncthreads();
        // shfl scan over NBC=448: waves 0..6
        int idx = w * 64 + lane;
        int v = 0, incl = 0;
        if (w < 7) {
            v = hist[idx];
            incl = v;
            #pragma unroll
            for (int o = 1; o < 64; o <<= 1) {
                int up = __shfl_up(incl, o, 64);
                if (lane >= o) incl += up;
            }
            if (lane == 63) wpart[w] = incl;
        }
        __syncthreads();
        if (t == 0) {
            int run = 0;
            #pragma unroll
            for (int k = 0; k < 7; ++k) { int x = wpart[k]; wpart[k] = run; run += x; }
        }
        __syncthreads();
        if (w < 7) {
            int excl = incl - v + wpart[w];
            if (idx < nb2) {
                csumG[(size_t)gb * (nb2 + 1) + idx] = excl;
                hist[idx] = excl;      // absolute scatter cursor
            }
        }
        if (t == 0) csumG[(size_t)gb * (nb2 + 1) + nb2] = ne;
        __syncthreads();
        #pragma unroll
        for (int k = 0; k < 4; ++k) {
            if (rr[k] >= 0) {
                int b = rr[k] >> CBITS;
                int pos = atomicAdd(&hist[b], 1);
                ebuf[pos] = ((rr[k] & (CB - 1)) << 17) | cc[k];  // col < 2^17
            }
        }
        __syncthreads();
        for (int i = t; i < ne; i += 1024)
            tilebuf[(size_t)gb * E_BLK + i] = ebuf[i];           // coalesced
    } else {
        int i = (gb - ebt) * 1024 + t;
        if (i < n4) {
            float4 f = reinterpret_cast<const float4*>(feat)[i];
            ushort4 u;
            u.x = f2bf(f.x); u.y = f2bf(f.y); u.z = f2bf(f.z); u.w = f2bf(f.w);
            reinterpret_cast<ushort4*>(feat_bf)[i] = u;
        }
    }
}

// ---------------- K2: per-bucket sort + 4-chain register gather ------------
template<int BF>
__global__ __launch_bounds__(1024, 8)
void agg10_kernel(const float* __restrict__ feat,
                  const unsigned short* __restrict__ feat_bf,
                  const int* __restrict__ tilebuf,
                  const int* __restrict__ csumG,
                  float* __restrict__ out, int n_nodes, int ebt, int nb2) {
    __shared__ int tstart[TMAX], tlen[TMAX], psum[TMAX];   // 6 KB
    __shared__ int scol[SCAP];                             // 18.4 KB
    __shared__ int cnt[CB], incl[CB], cur[CB], ddeg[CB];   // 4 KB
    __shared__ int wpart[8];

    int cb = blockIdx.x;
    int t = threadIdx.x;
    int w = t >> 6, lane = t & 63;
    int q = lane >> 3, sub = lane & 7;
    int rA = w * 16 + q;          // group's two rows (w<16, q<8)
    int rB = rA + 8;

    for (int i = t; i < TMAX; i += 1024) {
        int s = 0, l = 0;
        if (i < ebt) {
            s = csumG[(size_t)i * (nb2 + 1) + cb];
            l = csumG[(size_t)i * (nb2 + 1) + cb + 1] - s;
        }
        tstart[i] = s; tlen[i] = l;
    }
    if (t < CB) ddeg[t] = 0;
    __syncthreads();
    // inclusive shfl scan of tlen over TSCAN=448: waves 0..6
    {
        int idx = w * 64 + lane;
        int v = 0, ic = 0;
        if (w < 7) {
            v = tlen[idx];
            ic = v;
            #pragma unroll
            for (int o = 1; o < 64; o <<= 1) {
                int up = __shfl_up(ic, o, 64);
                if (lane >= o) ic += up;
            }
            if (lane == 63) wpart[w] = ic;
        }
        __syncthreads();
        if (t == 0) {
            int run = 0;
            #pragma unroll
            for (int k = 0; k < 7; ++k) { int x = wpart[k]; wpart[k] = run; run += x; }
        }
        __syncthreads();
        if (w < 7) psum[idx] = ic + wpart[w];
        __syncthreads();
    }
    int total = psum[ebt - 1];

    float acc[16];
    #pragma unroll
    for (int k = 0; k < 16; ++k) acc[k] = 0.f;

#define GATHER(cv, o0)                                                         \
    do {                                                                       \
        if (BF) {                                                              \
            uint4 d = *reinterpret_cast<const uint4*>(                         \
                feat_bf + (size_t)(cv)*D_FEAT + sub * 8);                      \
            acc[o0+0] += bf_lo(d.x); acc[o0+1] += bf_hi(d.x);                  \
            acc[o0+2] += bf_lo(d.y); acc[o0+3] += bf_hi(d.y);                  \
            acc[o0+4] += bf_lo(d.z); acc[o0+5] += bf_hi(d.z);                  \
            acc[o0+6] += bf_lo(d.w); acc[o0+7] += bf_hi(d.w);                  \
        } else {                                                               \
            float4 x0 = *reinterpret_cast<const float4*>(                      \
                feat + (size_t)(cv)*D_FEAT + sub * 8);                         \
            float4 x1 = *reinterpret_cast<const float4*>(                      \
                feat + (size_t)(cv)*D_FEAT + sub * 8 + 4);                     \
            acc[o0+0] += x0.x; acc[o0+1] += x0.y;                              \
            acc[o0+2] += x0.z; acc[o0+3] += x0.w;                              \
            acc[o0+4] += x1.x; acc[o0+5] += x1.y;                              \
            acc[o0+6] += x1.z; acc[o0+7] += x1.w;                              \
        }                                                                      \
    } while (0)

    // chunk loop over the flat edge stream (1 chunk for typical buckets)
    for (int L = 0; L < total; L += SCAP) {
        int R = min(L + SCAP, total);
        if (t < CB) cnt[t] = 0;
        __syncthreads();
        // fetch my flat edges via binary search on psum; cache pk in regs
        int pkr[PKN];
        #pragma unroll
        for (int k = 0; k < PKN; ++k) {
            int j = L + t + k * 1024;
            pkr[k] = -1;
            if (j < R) {
                int lo = 0, hi = ebt - 1;
                while (lo < hi) { int mid = (lo + hi) >> 1;
                                  if (psum[mid] > j) hi = mid; else lo = mid + 1; }
                int local = j - (psum[lo] - tlen[lo]);
                pkr[k] = tilebuf[(size_t)lo * E_BLK + tstart[lo] + local];
            }
        }
        #pragma unroll
        for (int k = 0; k < PKN; ++k)
            if (pkr[k] >= 0) atomicAdd(&cnt[((unsigned)pkr[k]) >> 17], 1);
        __syncthreads();
        // inclusive shfl scan of cnt over CB=256: waves 0..3
        {
            int idx = w * 64 + lane;
            int v = 0, ic = 0;
            if (w < 4) {
                v = cnt[idx];
                ic = v;
                #pragma unroll
                for (int o = 1; o < 64; o <<= 1) {
                    int up = __shfl_up(ic, o, 64);
                    if (lane >= o) ic += up;
                }
                if (lane == 63) wpart[w] = ic;
            }
            __syncthreads();
            if (t == 0) {
                int run = 0;
                #pragma unroll
                for (int k = 0; k < 4; ++k) { int x = wpart[k]; wpart[k] = run; run += x; }
            }
            __syncthreads();
            if (w < 4) {
                int ival = ic + wpart[w];
                incl[idx] = ival;
                cur[idx] = ival - v;
                ddeg[idx] += v;
            }
            __syncthreads();
        }
        // scatter cols row-grouped into scol
        #pragma unroll
        for (int k = 0; k < PKN; ++k) {
            if (pkr[k] >= 0) {
                int key = ((unsigned)pkr[k]) >> 17;
                scol[atomicAdd(&cur[key], 1)] = pkr[k] & 0x1FFFF;
            }
        }
        __syncthreads();
        // gather: 2 rows per 8-lane group, j-unroll x2 -> 4 chains in flight
        int cA = cnt[rA], sA = incl[rA] - cA;
        int cB2 = cnt[rB], sB = incl[rB] - cB2;
        int m = max(cA, cB2);
        for (int j = 0; j < m; j += 2) {
            int c00 = (j < cA)      ? scol[sA + j]     : -1;
            int c01 = (j + 1 < cA)  ? scol[sA + j + 1] : -1;
            int c10 = (j < cB2)     ? scol[sB + j]     : -1;
            int c11 = (j + 1 < cB2) ? scol[sB + j + 1] : -1;
            if (c00 >= 0) GATHER(c00, 0);
            if (c10 >= 0) GATHER(c10, 8);
            if (c01 >= 0) GATHER(c01, 0);
            if (c11 >= 0) GATHER(c11, 8);
        }
        __syncthreads();   // scol/cnt reused next chunk
    }
#undef GATHER

    // epilogue: out[r] = feat[r] + acc/max(deg,1)
    {
        int r = cb * CB + rA;
        if (r < n_nodes) {
            float inv = 1.0f / fmaxf((float)ddeg[rA], 1.0f);
            size_t off = (size_t)r * D_FEAT + sub * 8;
            float4 f0 = *reinterpret_cast<const float4*>(feat + off);
            float4 f1 = *reinterpret_cast<const float4*>(feat + off + 4);
            float4 o0, o1;
            o0.x = f0.x + acc[0] * inv; o0.y = f0.y + acc[1] * inv;
            o0.z = f0.z + acc[2] * inv; o0.w = f0.w + acc[3] * inv;
            o1.x = f1.x + acc[4] * inv; o1.y = f1.y + acc[5] * inv;
            o1.z = f1.z + acc[6] * inv; o1.w = f1.w + acc[7] * inv;
            *reinterpret_cast<float4*>(out + off) = o0;
            *reinterpret_cast<float4*>(out + off + 4) = o1;
        }
        r = cb * CB + rB;
        if (r < n_nodes) {
            float inv = 1.0f / fmaxf((float)ddeg[rB], 1.0f);
            size_t off = (size_t)r * D_FEAT + sub * 8;
            float4 f0 = *reinterpret_cast<const float4*>(feat + off);
            float4 f1 = *reinterpret_cast<const float4*>(feat + off + 4);
            float4 o0, o1;
            o0.x = f0.x + acc[8]  * inv; o0.y = f0.y + acc[9]  * inv;
            o0.z = f0.z + acc[10] * inv; o0.w = f0.w + acc[11] * inv;
            o1.x = f1.x + acc[12] * inv; o1.y = f1.y + acc[13] * inv;
            o1.z = f1.z + acc[14] * inv; o1.w = f1.w + acc[15] * inv;
            *reinterpret_cast<float4*>(out + off) = o0;
            *reinterpret_cast<float4*>(out + off + 4) = o1;
        }
    }
}

extern "C" void kernel_launch(void* const* d_in, const int* in_sizes, int n_in,
                              void* d_out, int out_size, void* d_ws, size_t ws_size,
                              hipStream_t stream) {
    const float* feat = (const float*)d_in[0];
    const int* row = (const int*)d_in[1];
    const int* col = (const int*)d_in[2];
    float* out = (float*)d_out;

    const int n_nodes = in_sizes[0] / D_FEAT;
    const int n_edges = in_sizes[1];
    const int nb2 = (n_nodes + CB - 1) / CB;              // 391 (<= NBC)
    const int ebt = (n_edges + E_BLK - 1) / E_BLK;        // 391 (<= TSCAN)
    const int n4 = n_nodes * D_FEAT / 4;                  // 1.6M float4s

    size_t tb_bytes  = (size_t)ebt * E_BLK * 4;           // 6.4 MB
    size_t cs_bytes  = (size_t)ebt * (nb2 + 1) * 4;       // 0.61 MB
    size_t bf_bytes  = (size_t)n_nodes * D_FEAT * 2;      // 12.8 MB

    size_t lean_need = tb_bytes + cs_bytes + 256;
    size_t fat_need  = lean_need + ((bf_bytes + 63) & ~(size_t)63);
    bool fat = (ws_size >= fat_need);

    char* ws = (char*)d_ws;
    size_t p = 0;
    int* tilebuf = (int*)(ws + p); p += tb_bytes;
    int* csumG   = (int*)(ws + p); p += cs_bytes;
    p = (p + 63) & ~(size_t)63;
    unsigned short* feat_bf = nullptr;
    if (fat) { feat_bf = (unsigned short*)(ws + p); }

    {
        int conv_blocks = fat ? (n4 + 1023) / 1024 : 0;
        bin9_conv_kernel<<<ebt + conv_blocks, 1024, 0, stream>>>(
            row, col, tilebuf, csumG, n_edges, ebt, nb2,
            feat, feat_bf, fat ? n4 : 0);
    }
    if (fat) {
        agg10_kernel<1><<<nb2, 1024, 0, stream>>>(
            feat, feat_bf, tilebuf, csumG, out, n_nodes, ebt, nb2);
    } else {
        agg10_kernel<0><<<nb2, 1024, 0, stream>>>(
            feat, nullptr, tilebuf, csumG, out, n_nodes, ebt, nb2);
    }
}

// Round 13
// 126.427 us; speedup vs baseline: 1.3265x; 1.0079x over previous
//
#include <hip/hip_runtime.h>

// N=100000 nodes, E=1600000 edges, D=64.
// Pipeline (2 launches):
//  K1 bin10_conv (1024 thr): per 4096-edge tile, LDS counting sort by 196-row
//     bucket (shfl scan) -> coalesced tilebuf + csumG; + bf16 conv blocks.
//  K2 agg12 (1024 thr, block = 196-row bucket, grid 511 ~= 512 block slots =
//     FULL residency from t=0, no tail): flat binary-search edge fetch
//     (reg-cached), 256-key-padded LDS counting sort (shfl scan),
//     2-rows-per-8-lane-group gather with x2 j-unroll = 4 chains/group.
#define D_FEAT 64
#define CB 196                // rows per bucket -> nb2 = ceil(N/196) = 511
#define CBPAD 256             // padded row arrays / scan width
#define NBC 512               // padded bucket-scan width (>= nb2), 8 waves x 64
#define E_BLK 4096            // edges per tile -> ebt = 391
#define TMAX 512              // padded tile storage (>= ebt)
#define SCAP 3840             // scol chunk capacity (bucket mean 3136, +12 sd)
#define PKN 4                 // ceil(SCAP/1024) reg-cached packed edges

__device__ inline unsigned short f2bf(float f) {
    unsigned u = __float_as_uint(f);
    u += 0x7FFFu + ((u >> 16) & 1u);   // RNE
    return (unsigned short)(u >> 16);
}
__device__ inline float bf_lo(unsigned u) { return __uint_as_float(u << 16); }
__device__ inline float bf_hi(unsigned u) { return __uint_as_float(u & 0xFFFF0000u); }

// ---------------- K1: tile counting sort (shfl scan) + bf16 conv -----------
__global__ __launch_bounds__(1024, 8)
void bin10_conv_kernel(const int* __restrict__ row, const int* __restrict__ col,
                       int* __restrict__ tilebuf,   // [ebt][E_BLK] bucket-sorted
                       int* __restrict__ csumG,     // [ebt][nb2+1] offsets
                       int n_edges, int ebt, int nb2,
                       const float* __restrict__ feat,
                       unsigned short* __restrict__ feat_bf, int n4) {
    int gb = blockIdx.x;
    int t = threadIdx.x;
    if (gb < ebt) {
        __shared__ int hist[NBC];      // counts -> absolute cursors
        __shared__ int ebuf[E_BLK];    // 16 KB sorted (pk = lr<<17 | col)
        __shared__ int wpart[8];
        int w = t >> 6, lane = t & 63;
        for (int i = t; i < NBC; i += 1024) hist[i] = 0;
        __syncthreads();
        int e0 = gb * E_BLK;
        int ne = min(E_BLK, n_edges - e0);
        int rr[4], cc[4];
        #pragma unroll
        for (int k = 0; k < 4; ++k) {
            int i = t + k * 1024;
            if (i < ne) { rr[k] = row[e0 + i]; cc[k] = col[e0 + i]; }
            else rr[k] = -1;
        }
        #pragma unroll
        for (int k = 0; k < 4; ++k)
            if (rr[k] >= 0) atomicAdd(&hist[rr[k] / CB], 1);
        __syncthreads();
        // shfl scan over NBC=512: waves 0..7
        int idx = w * 64 + lane;
        int v = 0, incl = 0;
        if (w < 8) {
            v = hist[idx];
            incl = v;
            #pragma unroll
            for (int o = 1; o < 64; o <<= 1) {
                int up = __shfl_up(incl, o, 64);
                if (lane >= o) incl += up;
            }
            if (lane == 63) wpart[w] = incl;
        }
        __syncthreads();
        if (t == 0) {
            int run = 0;
            #pragma unroll
            for (int k = 0; k < 8; ++k) { int x = wpart[k]; wpart[k] = run; run += x; }
        }
        __syncthreads();
        if (w < 8) {
            int excl = incl - v + wpart[w];
            if (idx < nb2) {
                csumG[(size_t)gb * (nb2 + 1) + idx] = excl;
                hist[idx] = excl;      // absolute scatter cursor
            }
        }
        if (t == 0) csumG[(size_t)gb * (nb2 + 1) + nb2] = ne;
        __syncthreads();
        #pragma unroll
        for (int k = 0; k < 4; ++k) {
            if (rr[k] >= 0) {
                int b = rr[k] / CB;
                int lr = rr[k] - b * CB;
                int pos = atomicAdd(&hist[b], 1);
                ebuf[pos] = (lr << 17) | cc[k];  // col < 2^17, lr < 256
            }
        }
        __syncthreads();
        for (int i = t; i < ne; i += 1024)
            tilebuf[(size_t)gb * E_BLK + i] = ebuf[i];           // coalesced
    } else {
        int i = (gb - ebt) * 1024 + t;
        if (i < n4) {
            float4 f = reinterpret_cast<const float4*>(feat)[i];
            ushort4 u;
            u.x = f2bf(f.x); u.y = f2bf(f.y); u.z = f2bf(f.z); u.w = f2bf(f.w);
            reinterpret_cast<ushort4*>(feat_bf)[i] = u;
        }
    }
}

// ---------------- K2: full-residency per-bucket sort + 4-chain gather ------
template<int BF>
__global__ __launch_bounds__(1024, 8)
void agg12_kernel(const float* __restrict__ feat,
                  const unsigned short* __restrict__ feat_bf,
                  const int* __restrict__ tilebuf,
                  const int* __restrict__ csumG,
                  float* __restrict__ out, int n_nodes, int ebt, int nb2) {
    __shared__ int tstart[TMAX], tlen[TMAX], psum[TMAX];       // 6 KB
    __shared__ int scol[SCAP];                                 // 15.4 KB
    __shared__ int cnt[CBPAD], incl[CBPAD], cur[CBPAD], ddeg[CBPAD]; // 4 KB
    __shared__ int wpart[8];

    int cb = blockIdx.x;
    int t = threadIdx.x;
    int w = t >> 6, lane = t & 63;
    int q = lane >> 3, sub = lane & 7;
    int rA = w * 16 + q;          // group's two local rows (covers 0..255)
    int rB = rA + 8;

    for (int i = t; i < TMAX; i += 1024) {
        int s = 0, l = 0;
        if (i < ebt) {
            s = csumG[(size_t)i * (nb2 + 1) + cb];
            l = csumG[(size_t)i * (nb2 + 1) + cb + 1] - s;
        }
        tstart[i] = s; tlen[i] = l;
    }
    if (t < CBPAD) ddeg[t] = 0;
    __syncthreads();
    // inclusive shfl scan of tlen over 448: waves 0..6 (ebt <= 448)
    {
        int idx = w * 64 + lane;
        int v = 0, ic = 0;
        if (w < 7) {
            v = tlen[idx];
            ic = v;
            #pragma unroll
            for (int o = 1; o < 64; o <<= 1) {
                int up = __shfl_up(ic, o, 64);
                if (lane >= o) ic += up;
            }
            if (lane == 63) wpart[w] = ic;
        }
        __syncthreads();
        if (t == 0) {
            int run = 0;
            #pragma unroll
            for (int k = 0; k < 7; ++k) { int x = wpart[k]; wpart[k] = run; run += x; }
        }
        __syncthreads();
        if (w < 7) psum[idx] = ic + wpart[w];
        __syncthreads();
    }
    int total = psum[ebt - 1];

    float acc[16];
    #pragma unroll
    for (int k = 0; k < 16; ++k) acc[k] = 0.f;

#define GATHER(cv, o0)                                                         \
    do {                                                                       \
        if (BF) {                                                              \
            uint4 d = *reinterpret_cast<const uint4*>(                         \
                feat_bf + (size_t)(cv)*D_FEAT + sub * 8);                      \
            acc[o0+0] += bf_lo(d.x); acc[o0+1] += bf_hi(d.x);                  \
            acc[o0+2] += bf_lo(d.y); acc[o0+3] += bf_hi(d.y);                  \
            acc[o0+4] += bf_lo(d.z); acc[o0+5] += bf_hi(d.z);                  \
            acc[o0+6] += bf_lo(d.w); acc[o0+7] += bf_hi(d.w);                  \
        } else {                                                               \
            float4 x0 = *reinterpret_cast<const float4*>(                      \
                feat + (size_t)(cv)*D_FEAT + sub * 8);                         \
            float4 x1 = *reinterpret_cast<const float4*>(                      \
                feat + (size_t)(cv)*D_FEAT + sub * 8 + 4);                     \
            acc[o0+0] += x0.x; acc[o0+1] += x0.y;                              \
            acc[o0+2] += x0.z; acc[o0+3] += x0.w;                              \
            acc[o0+4] += x1.x; acc[o0+5] += x1.y;                              \
            acc[o0+6] += x1.z; acc[o0+7] += x1.w;                              \
        }                                                                      \
    } while (0)

    // chunk loop over the flat edge stream (1 chunk for typical buckets)
    for (int L = 0; L < total; L += SCAP) {
        int R = min(L + SCAP, total);
        if (t < CBPAD) cnt[t] = 0;
        __syncthreads();
        // fetch my flat edges via binary search on psum; cache pk in regs
        int pkr[PKN];
        #pragma unroll
        for (int k = 0; k < PKN; ++k) {
            int j = L + t + k * 1024;
            pkr[k] = -1;
            if (j < R) {
                int lo = 0, hi = ebt - 1;
                while (lo < hi) { int mid = (lo + hi) >> 1;
                                  if (psum[mid] > j) hi = mid; else lo = mid + 1; }
                int local = j - (psum[lo] - tlen[lo]);
                pkr[k] = tilebuf[(size_t)lo * E_BLK + tstart[lo] + local];
            }
        }
        #pragma unroll
        for (int k = 0; k < PKN; ++k)
            if (pkr[k] >= 0) atomicAdd(&cnt[((unsigned)pkr[k]) >> 17], 1);
        __syncthreads();
        // inclusive shfl scan of cnt over CBPAD=256: waves 0..3
        {
            int idx = w * 64 + lane;
            int v = 0, ic = 0;
            if (w < 4) {
                v = cnt[idx];
                ic = v;
                #pragma unroll
                for (int o = 1; o < 64; o <<= 1) {
                    int up = __shfl_up(ic, o, 64);
                    if (lane >= o) ic += up;
                }
                if (lane == 63) wpart[w] = ic;
            }
            __syncthreads();
            if (t == 0) {
                int run = 0;
                #pragma unroll
                for (int k = 0; k < 4; ++k) { int x = wpart[k]; wpart[k] = run; run += x; }
            }
            __syncthreads();
            if (w < 4) {
                int ival = ic + wpart[w];
                incl[idx] = ival;
                cur[idx] = ival - v;
                ddeg[idx] += v;
            }
            __syncthreads();
        }
        // scatter cols row-grouped into scol
        #pragma unroll
        for (int k = 0; k < PKN; ++k) {
            if (pkr[k] >= 0) {
                int key = ((unsigned)pkr[k]) >> 17;
                scol[atomicAdd(&cur[key], 1)] = pkr[k] & 0x1FFFF;
            }
        }
        __syncthreads();
        // gather: 2 rows per 8-lane group, j-unroll x2 -> 4 chains in flight
        int cA = cnt[rA], sA = incl[rA] - cA;
        int cB2 = cnt[rB], sB = incl[rB] - cB2;
        int m = max(cA, cB2);
        for (int j = 0; j < m; j += 2) {
            int c00 = (j < cA)      ? scol[sA + j]     : -1;
            int c01 = (j + 1 < cA)  ? scol[sA + j + 1] : -1;
            int c10 = (j < cB2)     ? scol[sB + j]     : -1;
            int c11 = (j + 1 < cB2) ? scol[sB + j + 1] : -1;
            if (c00 >= 0) GATHER(c00, 0);
            if (c10 >= 0) GATHER(c10, 8);
            if (c01 >= 0) GATHER(c01, 0);
            if (c11 >= 0) GATHER(c11, 8);
        }
        __syncthreads();   // scol/cnt reused next chunk
    }
#undef GATHER

    // epilogue: out[r] = feat[r] + acc/max(deg,1); guard lr < CB (rows
    // 196..255 of the padded space belong to the NEXT bucket - never write)
    {
        int r = cb * CB + rA;
        if (rA < CB && r < n_nodes) {
            float inv = 1.0f / fmaxf((float)ddeg[rA], 1.0f);
            size_t off = (size_t)r * D_FEAT + sub * 8;
            float4 f0 = *reinterpret_cast<const float4*>(feat + off);
            float4 f1 = *reinterpret_cast<const float4*>(feat + off + 4);
            float4 o0, o1;
            o0.x = f0.x + acc[0] * inv; o0.y = f0.y + acc[1] * inv;
            o0.z = f0.z + acc[2] * inv; o0.w = f0.w + acc[3] * inv;
            o1.x = f1.x + acc[4] * inv; o1.y = f1.y + acc[5] * inv;
            o1.z = f1.z + acc[6] * inv; o1.w = f1.w + acc[7] * inv;
            *reinterpret_cast<float4*>(out + off) = o0;
            *reinterpret_cast<float4*>(out + off + 4) = o1;
        }
        r = cb * CB + rB;
        if (rB < CB && r < n_nodes) {
            float inv = 1.0f / fmaxf((float)ddeg[rB], 1.0f);
            size_t off = (size_t)r * D_FEAT + sub * 8;
            float4 f0 = *reinterpret_cast<const float4*>(feat + off);
            float4 f1 = *reinterpret_cast<const float4*>(feat + off + 4);
            float4 o0, o1;
            o0.x = f0.x + acc[8]  * inv; o0.y = f0.y + acc[9]  * inv;
            o0.z = f0.z + acc[10] * inv; o0.w = f0.w + acc[11] * inv;
            o1.x = f1.x + acc[12] * inv; o1.y = f1.y + acc[13] * inv;
            o1.z = f1.z + acc[14] * inv; o1.w = f1.w + acc[15] * inv;
            *reinterpret_cast<float4*>(out + off) = o0;
            *reinterpret_cast<float4*>(out + off + 4) = o1;
        }
    }
}

extern "C" void kernel_launch(void* const* d_in, const int* in_sizes, int n_in,
                              void* d_out, int out_size, void* d_ws, size_t ws_size,
                              hipStream_t stream) {
    const float* feat = (const float*)d_in[0];
    const int* row = (const int*)d_in[1];
    const int* col = (const int*)d_in[2];
    float* out = (float*)d_out;

    const int n_nodes = in_sizes[0] / D_FEAT;
    const int n_edges = in_sizes[1];
    const int nb2 = (n_nodes + CB - 1) / CB;              // 511 (<= NBC)
    const int ebt = (n_edges + E_BLK - 1) / E_BLK;        // 391 (<= 448)
    const int n4 = n_nodes * D_FEAT / 4;                  // 1.6M float4s

    size_t tb_bytes  = (size_t)ebt * E_BLK * 4;           // 6.4 MB
    size_t cs_bytes  = (size_t)ebt * (nb2 + 1) * 4;       // 0.80 MB
    size_t bf_bytes  = (size_t)n_nodes * D_FEAT * 2;      // 12.8 MB

    size_t lean_need = tb_bytes + cs_bytes + 256;
    size_t fat_need  = lean_need + ((bf_bytes + 63) & ~(size_t)63);
    bool fat = (ws_size >= fat_need);

    char* ws = (char*)d_ws;
    size_t p = 0;
    int* tilebuf = (int*)(ws + p); p += tb_bytes;
    int* csumG   = (int*)(ws + p); p += cs_bytes;
    p = (p + 63) & ~(size_t)63;
    unsigned short* feat_bf = nullptr;
    if (fat) { feat_bf = (unsigned short*)(ws + p); }

    {
        int conv_blocks = fat ? (n4 + 1023) / 1024 : 0;
        bin10_conv_kernel<<<ebt + conv_blocks, 1024, 0, stream>>>(
            row, col, tilebuf, csumG, n_edges, ebt, nb2,
            feat, feat_bf, fat ? n4 : 0);
    }
    if (fat) {
        agg12_kernel<1><<<nb2, 1024, 0, stream>>>(
            feat, feat_bf, tilebuf, csumG, out, n_nodes, ebt, nb2);
    } else {
        agg12_kernel<0><<<nb2, 1024, 0, stream>>>(
            feat, nullptr, tilebuf, csumG, out, n_nodes, ebt, nb2);
    }
}